// Round 4
// baseline (327.075 us; speedup 1.0000x reference)
//
#include <hip/hip_runtime.h>
#include <hip/hip_bf16.h>
#include <math.h>

// Problem constants
#define BATCH 64
#define SEQ   512
#define DIM   768
#define NW    256              // MAX_WORDS
#define NT    (BATCH * NW)     // 16384 tokens
#define KDIM  1536             // 2*DIM
#define HID   256              // router hidden
#define NL    7                // num labels

typedef __bf16 bf16_t;
typedef bf16_t bf16x4 __attribute__((ext_vector_type(4)));
typedef bf16_t bf16x8 __attribute__((ext_vector_type(8)));
typedef float  f32x4  __attribute__((ext_vector_type(4)));

// ---------------------------------------------------------------------------
// Kernel 1: convert router_w1 (1536 x 256 fp32, [k][n]) -> w1t (256 x 1536
// bf16, [n][k]).  Grid 48 blocks x 32 k-rows. Coalesced loads, LDS transpose
// (stride 257), each thread writes one n-row's 64 B (full L2 lines).
// ---------------------------------------------------------------------------
__global__ __launch_bounds__(256) void convert_w1_kernel(
    const float* __restrict__ w1, bf16_t* __restrict__ w1t)
{
    __shared__ float tile[32 * 257];
    int tid = threadIdx.x;
    int k0  = blockIdx.x * 32;

    for (int kk = 0; kk < 32; kk++)                    // coalesced 1 KB per iter
        tile[kk * 257 + tid] = w1[(size_t)(k0 + kk) * HID + tid];
    __syncthreads();

    int n = tid;
    #pragma unroll
    for (int c = 0; c < 4; c++) {
        bf16x8 v;
        #pragma unroll
        for (int j = 0; j < 8; j++)
            v[j] = (bf16_t)tile[(c * 8 + j) * 257 + n];
        *(bf16x8*)(w1t + (size_t)n * KDIM + k0 + c * 8) = v;  // 16 B, lane-contig 64 B
    }
}

// ---------------------------------------------------------------------------
// Kernel 2: starts table. starts[t][b][w] = lower_bound(ids[b], w); entry 256
// = SEQ. Grid 128 = 2 tensors x 64 batches.
// ---------------------------------------------------------------------------
__global__ __launch_bounds__(256) void starts_kernel(
    const int* __restrict__ idh, const int* __restrict__ idr,
    int* __restrict__ starts)
{
    int blk = blockIdx.x;
    int t = blk >> 6;
    int b = blk & 63;
    const int* ids = (t ? idr : idh) + b * SEQ;
    int w = threadIdx.x;
    int lo = 0, hi = SEQ;
    while (lo < hi) {
        int m = (lo + hi) >> 1;
        if (ids[m] < w) lo = m + 1; else hi = m;
    }
    int* row = starts + blk * 257;
    row[w] = lo;
    if (w == 0) row[256] = SEQ;
}

// ---------------------------------------------------------------------------
// Kernel 3: segment-mean align with BATCHED loads.
// Wave-task = (b, tensor, 4-word chunk) -> 8192 tasks, grid 2048 x 256.
// Per word: n = seg length (wave-uniform). Fast path n<=6: six scalar-branch-
// guarded load-triples issued back-to-back (up to 18 KB in flight / wave),
// ONE waitcnt, then sum. Tail loop only for n>6 (~0.45% of words).
// ---------------------------------------------------------------------------
__global__ __launch_bounds__(256) void align_kernel(
    const float* __restrict__ hh, const float* __restrict__ hr,
    const int* __restrict__ starts, bf16_t* __restrict__ X)
{
    int tid  = threadIdx.x;
    int lane = tid & 63;
    int wv   = tid >> 6;
    int task = blockIdx.x * 4 + wv;       // 8192 tasks
    int b = task >> 7;                    // 128 tasks per batch
    int t = (task >> 6) & 1;
    int c = task & 63;
    int w0 = c * 4;

    const int*   st    = starts + (t * 64 + b) * 257;
    const f32x4* base4 = (const f32x4*)((t ? hr : hh) + (size_t)b * SEQ * DIM);
    bf16_t*      dstb  = X + (size_t)b * NW * KDIM + t * DIM;

    int lo = st[w0];
    #pragma unroll 1
    for (int w = w0; w < w0 + 4; w++) {
        int hi = st[w + 1];
        int n  = hi - lo;
        int ns = __builtin_amdgcn_readfirstlane(n);
        bf16_t* xr = dstb + (size_t)w * KDIM;

        if (ns <= 0) {
            bf16x4 z = {};
            *(bf16x4*)(xr + lane * 4)         = z;
            *(bf16x4*)(xr + (lane + 64) * 4)  = z;
            *(bf16x4*)(xr + (lane + 128) * 4) = z;
        } else {
            const f32x4* r0 = base4 + (size_t)lo * (DIM / 4);
            f32x4 z = {0.f, 0.f, 0.f, 0.f};
            f32x4 l0a=z,l0b=z,l0c=z, l1a=z,l1b=z,l1c=z, l2a=z,l2b=z,l2c=z;
            f32x4 l3a=z,l3b=z,l3c=z, l4a=z,l4b=z,l4c=z, l5a=z,l5b=z,l5c=z;
            // batched, branch-guarded loads (no data deps between them)
            {                 l0a=r0[lane]; l0b=r0[lane+64]; l0c=r0[lane+128]; }
            if (ns > 1) { const f32x4* r=r0+192;   l1a=r[lane]; l1b=r[lane+64]; l1c=r[lane+128]; }
            if (ns > 2) { const f32x4* r=r0+384;   l2a=r[lane]; l2b=r[lane+64]; l2c=r[lane+128]; }
            if (ns > 3) { const f32x4* r=r0+576;   l3a=r[lane]; l3b=r[lane+64]; l3c=r[lane+128]; }
            if (ns > 4) { const f32x4* r=r0+768;   l4a=r[lane]; l4b=r[lane+64]; l4c=r[lane+128]; }
            if (ns > 5) { const f32x4* r=r0+960;   l5a=r[lane]; l5b=r[lane+64]; l5c=r[lane+128]; }

            f32x4 a0 = z, a1 = z, a2 = z;
            if (ns > 6) {                         // rare tail
                for (int s = lo + 6; s < hi; s++) {
                    const f32x4* r = base4 + (size_t)s * (DIM / 4);
                    a0 += r[lane]; a1 += r[lane + 64]; a2 += r[lane + 128];
                }
            }
            a0 += (l0a + l1a) + (l2a + l3a) + (l4a + l5a);
            a1 += (l0b + l1b) + (l2b + l3b) + (l4b + l5b);
            a2 += (l0c + l1c) + (l2c + l3c) + (l4c + l5c);

            float inv = 1.0f / (float)n;
            bf16x4 o0, o1, o2;
            #pragma unroll
            for (int e = 0; e < 4; e++) {
                o0[e] = (bf16_t)(a0[e] * inv);
                o1[e] = (bf16_t)(a1[e] * inv);
                o2[e] = (bf16_t)(a2[e] * inv);
            }
            *(bf16x4*)(xr + lane * 4)         = o0;
            *(bf16x4*)(xr + (lane + 64) * 4)  = o1;
            *(bf16x4*)(xr + (lane + 128) * 4) = o2;
        }
        lo = hi;
    }
}

// ---------------------------------------------------------------------------
// Kernel 4: LDS-free router GEMM (bf16 MFMA) -> alpha.
// Grid 512 x 256 (4 waves). Block owns 32 tokens; wave wv owns cols
// [64*wv, 64*wv+64). Fragments loaded straight from global:
//   A: X[tok0 + mi*16 + row16][kcc*32 + quad*8 + j]      (HBM/L1, x4 wave reuse)
//   B: w1t[wv*64 + ni*16 + row16][kcc*32 + quad*8 + j]   (L2-resident, 786 KB)
// No barriers -> K-loop software-pipelines freely.
// ---------------------------------------------------------------------------
__global__ __launch_bounds__(256) void gemm_alpha_kernel(
    const bf16_t* __restrict__ X, const bf16_t* __restrict__ w1t,
    const float* __restrict__ b1, const float* __restrict__ w2,
    const float* __restrict__ b2, float* __restrict__ out)
{
    __shared__ float alpha_acc[32];

    int tid   = threadIdx.x;
    int lane  = tid & 63;
    int wv    = tid >> 6;
    int row16 = lane & 15;
    int quad  = lane >> 4;
    int tok0  = blockIdx.x * 32;

    f32x4 acc[2][4];
    #pragma unroll
    for (int mi = 0; mi < 2; mi++)
        #pragma unroll
        for (int ni = 0; ni < 4; ni++)
            acc[mi][ni] = (f32x4){0.f, 0.f, 0.f, 0.f};

    const bf16_t* aptr = X   + (size_t)(tok0 + row16) * KDIM + quad * 8;
    const bf16_t* bptr = w1t + (size_t)(wv * 64 + row16) * KDIM + quad * 8;

    #pragma unroll 4
    for (int kcc = 0; kcc < KDIM / 32; kcc++) {       // 48 K-steps of 32
        bf16x8 af[2], bfg[4];
        #pragma unroll
        for (int mi = 0; mi < 2; mi++)
            af[mi] = *(const bf16x8*)(aptr + (size_t)mi * 16 * KDIM + kcc * 32);
        #pragma unroll
        for (int ni = 0; ni < 4; ni++)
            bfg[ni] = *(const bf16x8*)(bptr + (size_t)ni * 16 * KDIM + kcc * 32);
        #pragma unroll
        for (int mi = 0; mi < 2; mi++)
            #pragma unroll
            for (int ni = 0; ni < 4; ni++)
                acc[mi][ni] = __builtin_amdgcn_mfma_f32_16x16x32_bf16(
                    af[mi], bfg[ni], acc[mi][ni], 0, 0, 0);
    }

    // alpha = sigmoid( relu(hdn + b1) . w2 + b2 ), C layout: col=lane&15,
    // row = quad*4 + reg
    float w2v[4], b1v[4];
    #pragma unroll
    for (int ni = 0; ni < 4; ni++) {
        int col = wv * 64 + ni * 16 + row16;
        w2v[ni] = w2[col];
        b1v[ni] = b1[col];
    }
    if (tid < 32) alpha_acc[tid] = 0.f;
    __syncthreads();

    #pragma unroll
    for (int mi = 0; mi < 2; mi++) {
        #pragma unroll
        for (int r = 0; r < 4; r++) {
            float p = 0.f;
            #pragma unroll
            for (int ni = 0; ni < 4; ni++) {
                float v = acc[mi][ni][r] + b1v[ni];
                v = v > 0.f ? v : 0.f;
                p += v * w2v[ni];
            }
            p += __shfl_xor(p, 1);
            p += __shfl_xor(p, 2);
            p += __shfl_xor(p, 4);
            p += __shfl_xor(p, 8);
            if (row16 == 0)
                atomicAdd(&alpha_acc[mi * 16 + quad * 4 + r], p);
        }
    }
    __syncthreads();
    if (tid < 32) {
        float a = 1.f / (1.f + expf(-(alpha_acc[tid] + b2[0])));
        out[(size_t)NT * NL + tok0 + tid] = a;
    }
}

// ---------------------------------------------------------------------------
// Kernel 5: blend + head + l2. 8 tokens per wave (lane-group of 8):
// butterflies are wave-wide -> 24 shfl per 8 tokens. hw staged in LDS
// transposed [l][d]; reads broadcast across the 8 groups (2-way alias max).
// Grid 512 x 256.
// ---------------------------------------------------------------------------
__global__ __launch_bounds__(256) void blend_kernel(
    const bf16_t* __restrict__ X, const float* __restrict__ hw,
    const float* __restrict__ hb, float* __restrict__ out)
{
    __shared__ float hws[NL * DIM];       // [l][d], 21504 B
    int tid  = threadIdx.x;
    int lane = tid & 63;
    int wv   = tid >> 6;

    for (int i = tid; i < DIM * NL; i += 256) {
        int d = i / NL, l = i - d * NL;   // source [d][l]
        hws[l * DIM + d] = hw[i];
    }
    __syncthreads();

    int g   = lane >> 3;                  // token within wave
    int u   = lane & 7;                   // dim-slice
    int tok = blockIdx.x * 32 + wv * 8 + g;

    float a = out[(size_t)NT * NL + tok];
    const bf16_t* xrow = X + (size_t)tok * KDIM;

    float lg[NL] = {0.f, 0.f, 0.f, 0.f, 0.f, 0.f, 0.f};
    float l2 = 0.f;

    #pragma unroll
    for (int k = 0; k < 12; k++) {
        int d0 = (k * 8 + u) * 8;                       // 8 dims per chunk
        bf16x8 hp = *(const bf16x8*)(xrow + d0);        // 16 B/lane, 128 B/group
        bf16x8 rp = *(const bf16x8*)(xrow + DIM + d0);
        float bl[8];
        #pragma unroll
        for (int e = 0; e < 8; e++) {
            float hhv = (float)hp[e];
            float hrv = (float)rp[e];
            float df  = hhv - hrv;
            bl[e] = fmaf(a, df, hrv);                   // a*hh + (1-a)*hr
            l2 = fmaf(df, df, l2);
        }
        #pragma unroll
        for (int l = 0; l < NL; l++) {
            f32x4 wA = *(const f32x4*)(&hws[l * DIM + d0]);
            f32x4 wB = *(const f32x4*)(&hws[l * DIM + d0 + 4]);
            lg[l] += bl[0]*wA[0] + bl[1]*wA[1] + bl[2]*wA[2] + bl[3]*wA[3]
                   + bl[4]*wB[0] + bl[5]*wB[1] + bl[6]*wB[2] + bl[7]*wB[3];
        }
    }

    // reduce over the 8 dim-slices: wave-wide, all 8 tokens at once
    #pragma unroll
    for (int off = 1; off < 8; off <<= 1) {
        #pragma unroll
        for (int l = 0; l < NL; l++) lg[l] += __shfl_xor(lg[l], off);
        l2 += __shfl_xor(l2, off);
    }

    if (u < NL) {
        float v = (u == 0) ? lg[0] : (u == 1) ? lg[1] : (u == 2) ? lg[2]
                : (u == 3) ? lg[3] : (u == 4) ? lg[4] : (u == 5) ? lg[5] : lg[6];
        out[(size_t)tok * NL + u] = v + hb[u];
    } else {
        out[(size_t)NT * NL + NT + tok] = sqrtf(l2);
    }
}

// ---------------------------------------------------------------------------
extern "C" void kernel_launch(void* const* d_in, const int* in_sizes, int n_in,
                              void* d_out, int out_size, void* d_ws, size_t ws_size,
                              hipStream_t stream)
{
    const float* hh  = (const float*)d_in[0];
    const float* hr  = (const float*)d_in[1];
    const int*   idh = (const int*)d_in[2];
    const int*   idr = (const int*)d_in[3];
    const float* w1  = (const float*)d_in[5];
    const float* b1  = (const float*)d_in[6];
    const float* w2  = (const float*)d_in[7];
    const float* b2  = (const float*)d_in[8];
    const float* hw  = (const float*)d_in[9];
    const float* hb  = (const float*)d_in[10];
    float* out = (float*)d_out;

    bf16_t* X      = (bf16_t*)d_ws;                        // 50.33 MB
    bf16_t* w1t    = X + (size_t)NT * KDIM;                // 0.79 MB ([n][k])
    int*    starts = (int*)(w1t + (size_t)HID * KDIM);     // 263 KB

    convert_w1_kernel<<<48, 256, 0, stream>>>(w1, w1t);
    starts_kernel<<<128, 256, 0, stream>>>(idh, idr, starts);
    align_kernel<<<2048, 256, 0, stream>>>(hh, hr, starts, X);
    gemm_alpha_kernel<<<512, 256, 0, stream>>>(X, w1t, b1, w2, b2, out);
    blend_kernel<<<512, 256, 0, stream>>>(X, hw, hb, out);
}

// Round 5
// 291.056 us; speedup vs baseline: 1.1238x; 1.1238x over previous
//
#include <hip/hip_runtime.h>
#include <hip/hip_bf16.h>
#include <math.h>

// Problem constants
#define BATCH 64
#define SEQ   512
#define DIM   768
#define NW    256              // MAX_WORDS
#define NT    (BATCH * NW)     // 16384 tokens
#define KDIM  1536             // 2*DIM
#define HID   256              // router hidden
#define NL    7                // num labels

// GEMM tiling
#define BM  32
#define BK  64
#define BKP 72                 // padded LDS row stride (bf16) -> 144 B
#define NKT (KDIM / BK)        // 24

typedef __bf16 bf16_t;
typedef bf16_t bf16x4 __attribute__((ext_vector_type(4)));
typedef bf16_t bf16x8 __attribute__((ext_vector_type(8)));
typedef float  f32x4  __attribute__((ext_vector_type(4)));

__device__ __forceinline__ void madv(f32x4& a, const f32x4& v, float s) {
    a[0] = fmaf(v[0], s, a[0]);
    a[1] = fmaf(v[1], s, a[1]);
    a[2] = fmaf(v[2], s, a[2]);
    a[3] = fmaf(v[3], s, a[3]);
}

// ---------------------------------------------------------------------------
// Kernel 1: convert router_w1 (1536 x 256 fp32) -> bf16 K-major tiles
// w1t[kc][n][kk].  Grid 192: block=(kc,kg) handles 8 k-rows.
// ---------------------------------------------------------------------------
__global__ __launch_bounds__(256) void convert_w1_kernel(
    const float* __restrict__ w1, bf16_t* __restrict__ w1t)
{
    int kc = blockIdx.x >> 3;        // 0..23
    int kg = blockIdx.x & 7;         // 0..7
    int n  = threadIdx.x;            // 0..255
    bf16x8 v;
    #pragma unroll
    for (int j = 0; j < 8; j++)
        v[j] = (bf16_t)w1[(size_t)(kc * 64 + kg * 8 + j) * HID + n];
    *(bf16x8*)(w1t + (size_t)kc * (HID * BK) + n * BK + kg * 8) = v;
}

// ---------------------------------------------------------------------------
// Kernel 2: starts table. starts[t][b][w] = lower_bound(ids[b], w); entry 256
// = SEQ. Grid 128 = 2 tensors x 64 batches.
// ---------------------------------------------------------------------------
__global__ __launch_bounds__(256) void starts_kernel(
    const int* __restrict__ idh, const int* __restrict__ idr,
    int* __restrict__ starts)
{
    int blk = blockIdx.x;
    int t = blk >> 6;
    int b = blk & 63;
    const int* ids = (t ? idr : idh) + b * SEQ;
    int w = threadIdx.x;
    int lo = 0, hi = SEQ;
    while (lo < hi) {
        int m = (lo + hi) >> 1;
        if (ids[m] < w) lo = m + 1; else hi = m;
    }
    int* row = starts + blk * 257;
    row[w] = lo;
    if (w == 0) row[256] = SEQ;
}

// ---------------------------------------------------------------------------
// Kernel 3: segment-mean align, UNCONDITIONAL clamped batched loads.
// Wave-task = (b, tensor, 4-word chunk) -> 8192 tasks, grid 2048 x 256.
// Per word (n = seg length, wave-uniform): always load 6 rows with index
// min(s, n-1) -- duplicates hit L1, no extra HBM traffic, NO branches in the
// load path -> 18 independent dwordx4 loads (18 KB/wave) stay in flight.
// Combine with scalar 0/1 weights. Tail loop only for n>6 (~0.45%).
// __launch_bounds__(256,2): VGPR budget 256 so the scheduler doesn't
// serialize the loads to save registers (R4 failure mode: VGPR_Count=64).
// ---------------------------------------------------------------------------
__global__ __launch_bounds__(256, 2) void align_kernel(
    const float* __restrict__ hh, const float* __restrict__ hr,
    const int* __restrict__ starts, bf16_t* __restrict__ X)
{
    int tid  = threadIdx.x;
    int lane = tid & 63;
    int wv   = tid >> 6;
    int task = blockIdx.x * 4 + wv;       // 8192 tasks
    int b = task >> 7;
    int t = (task >> 6) & 1;
    int c = task & 63;
    int w0 = c * 4;

    const int*   st    = starts + (t * 64 + b) * 257;
    const f32x4* base4 = (const f32x4*)((t ? hr : hh) + (size_t)b * SEQ * DIM);
    bf16_t*      dstb  = X + (size_t)b * NW * KDIM + t * DIM;

    int lo = st[w0];
    #pragma unroll 1
    for (int w = w0; w < w0 + 4; w++) {
        int hi = st[w + 1];
        int ns = __builtin_amdgcn_readfirstlane(hi - lo);
        bf16_t* xr = dstb + (size_t)w * KDIM;

        if (ns <= 0) {
            bf16x4 z = {};
            *(bf16x4*)(xr + lane * 4)         = z;
            *(bf16x4*)(xr + (lane + 64) * 4)  = z;
            *(bf16x4*)(xr + (lane + 128) * 4) = z;
        } else {
            int nm1 = ns - 1;
            const f32x4* p0 = base4 + (size_t)lo * 192;
            const f32x4* p1 = base4 + (size_t)(lo + (1 < ns ? 1 : nm1)) * 192;
            const f32x4* p2 = base4 + (size_t)(lo + (2 < ns ? 2 : nm1)) * 192;
            const f32x4* p3 = base4 + (size_t)(lo + (3 < ns ? 3 : nm1)) * 192;
            const f32x4* p4 = base4 + (size_t)(lo + (4 < ns ? 4 : nm1)) * 192;
            const f32x4* p5 = base4 + (size_t)(lo + (5 < ns ? 5 : nm1)) * 192;

            // 18 unconditional independent loads
            f32x4 l0a = p0[lane], l0b = p0[lane + 64], l0c = p0[lane + 128];
            f32x4 l1a = p1[lane], l1b = p1[lane + 64], l1c = p1[lane + 128];
            f32x4 l2a = p2[lane], l2b = p2[lane + 64], l2c = p2[lane + 128];
            f32x4 l3a = p3[lane], l3b = p3[lane + 64], l3c = p3[lane + 128];
            f32x4 l4a = p4[lane], l4b = p4[lane + 64], l4c = p4[lane + 128];
            f32x4 l5a = p5[lane], l5b = p5[lane + 64], l5c = p5[lane + 128];

            float k1 = (1 < ns) ? 1.f : 0.f;
            float k2 = (2 < ns) ? 1.f : 0.f;
            float k3 = (3 < ns) ? 1.f : 0.f;
            float k4 = (4 < ns) ? 1.f : 0.f;
            float k5 = (5 < ns) ? 1.f : 0.f;

            f32x4 a0 = l0a, a1 = l0b, a2 = l0c;
            madv(a0, l1a, k1); madv(a1, l1b, k1); madv(a2, l1c, k1);
            madv(a0, l2a, k2); madv(a1, l2b, k2); madv(a2, l2c, k2);
            madv(a0, l3a, k3); madv(a1, l3b, k3); madv(a2, l3c, k3);
            madv(a0, l4a, k4); madv(a1, l4b, k4); madv(a2, l4c, k4);
            madv(a0, l5a, k5); madv(a1, l5b, k5); madv(a2, l5c, k5);

            if (ns > 6) {                         // rare tail (~0.45%)
                for (int s = lo + 6; s < lo + ns; s++) {
                    const f32x4* r = base4 + (size_t)s * 192;
                    a0 += r[lane]; a1 += r[lane + 64]; a2 += r[lane + 128];
                }
            }

            float inv = 1.0f / (float)ns;
            bf16x4 o0, o1, o2;
            #pragma unroll
            for (int e = 0; e < 4; e++) {
                o0[e] = (bf16_t)(a0[e] * inv);
                o1[e] = (bf16_t)(a1[e] * inv);
                o2[e] = (bf16_t)(a2[e] * inv);
            }
            *(bf16x4*)(xr + lane * 4)         = o0;
            *(bf16x4*)(xr + (lane + 64) * 4)  = o1;
            *(bf16x4*)(xr + (lane + 128) * 4) = o2;
        }
        lo = hi;
    }
}

// ---------------------------------------------------------------------------
// Kernel 4: router GEMM (bf16 MFMA) via LDS -> alpha.  (R3 version — the
// faster of the two measured variants.)
// ---------------------------------------------------------------------------
__global__ __launch_bounds__(256) void gemm_alpha_kernel(
    const bf16_t* __restrict__ X, const bf16_t* __restrict__ w1t,
    const float* __restrict__ b1, const float* __restrict__ w2,
    const float* __restrict__ b2, float* __restrict__ out)
{
    __shared__ __align__(16) bf16_t Xs[BM][BKP];
    __shared__ __align__(16) bf16_t Ws[HID][BKP];
    __shared__ float alpha_acc[BM];

    int tid   = threadIdx.x;
    int lane  = tid & 63;
    int wv    = tid >> 6;
    int row16 = lane & 15;
    int quad  = lane >> 4;
    int tok0  = blockIdx.x * BM;

    f32x4 acc[2][4];
    #pragma unroll
    for (int mi = 0; mi < 2; mi++)
        #pragma unroll
        for (int ni = 0; ni < 4; ni++)
            acc[mi][ni] = (f32x4){0.f, 0.f, 0.f, 0.f};

    int xr = tid >> 3;
    int xc = tid & 7;

    for (int kc = 0; kc < NKT; kc++) {
        {
            const uint4* src = (const uint4*)(X + (size_t)(tok0 + xr) * KDIM + kc * BK + xc * 8);
            *(uint4*)(&Xs[xr][xc * 8]) = *src;
        }
        {
            const uint4* srcb = (const uint4*)(w1t + (size_t)kc * (HID * BK));
            #pragma unroll
            for (int i = 0; i < 8; i++) {
                int cidx = tid + i * 256;
                *(uint4*)(&Ws[cidx >> 3][(cidx & 7) * 8]) = srcb[cidx];
            }
        }
        __syncthreads();
        #pragma unroll
        for (int kk2 = 0; kk2 < 2; kk2++) {
            bf16x8 af[2], bfg[4];
            #pragma unroll
            for (int mi = 0; mi < 2; mi++)
                af[mi] = *(const bf16x8*)(&Xs[mi * 16 + row16][kk2 * 32 + quad * 8]);
            #pragma unroll
            for (int ni = 0; ni < 4; ni++)
                bfg[ni] = *(const bf16x8*)(&Ws[wv * 64 + ni * 16 + row16][kk2 * 32 + quad * 8]);
            #pragma unroll
            for (int mi = 0; mi < 2; mi++)
                #pragma unroll
                for (int ni = 0; ni < 4; ni++)
                    acc[mi][ni] = __builtin_amdgcn_mfma_f32_16x16x32_bf16(
                        af[mi], bfg[ni], acc[mi][ni], 0, 0, 0);
        }
        __syncthreads();
    }

    float w2v[4], b1v[4];
    #pragma unroll
    for (int ni = 0; ni < 4; ni++) {
        int col = wv * 64 + ni * 16 + row16;
        w2v[ni] = w2[col];
        b1v[ni] = b1[col];
    }
    if (tid < BM) alpha_acc[tid] = 0.f;
    __syncthreads();

    #pragma unroll
    for (int mi = 0; mi < 2; mi++) {
        #pragma unroll
        for (int r = 0; r < 4; r++) {
            float p = 0.f;
            #pragma unroll
            for (int ni = 0; ni < 4; ni++) {
                float v = acc[mi][ni][r] + b1v[ni];
                v = v > 0.f ? v : 0.f;
                p += v * w2v[ni];
            }
            p += __shfl_xor(p, 1);
            p += __shfl_xor(p, 2);
            p += __shfl_xor(p, 4);
            p += __shfl_xor(p, 8);
            if (row16 == 0)
                atomicAdd(&alpha_acc[mi * 16 + quad * 4 + r], p);
        }
    }
    __syncthreads();
    if (tid < BM) {
        float a = 1.f / (1.f + expf(-(alpha_acc[tid] + b2[0])));
        out[(size_t)NT * NL + tok0 + tid] = a;
    }
}

// ---------------------------------------------------------------------------
// Kernel 5: blend + head + l2. 8 tokens per wave (R4 version). Grid 512.
// ---------------------------------------------------------------------------
__global__ __launch_bounds__(256) void blend_kernel(
    const bf16_t* __restrict__ X, const float* __restrict__ hw,
    const float* __restrict__ hb, float* __restrict__ out)
{
    __shared__ float hws[NL * DIM];       // [l][d]
    int tid  = threadIdx.x;
    int lane = tid & 63;
    int wv   = tid >> 6;

    for (int i = tid; i < DIM * NL; i += 256) {
        int d = i / NL, l = i - d * NL;
        hws[l * DIM + d] = hw[i];
    }
    __syncthreads();

    int g   = lane >> 3;
    int u   = lane & 7;
    int tok = blockIdx.x * 32 + wv * 8 + g;

    float a = out[(size_t)NT * NL + tok];
    const bf16_t* xrow = X + (size_t)tok * KDIM;

    float lg[NL] = {0.f, 0.f, 0.f, 0.f, 0.f, 0.f, 0.f};
    float l2 = 0.f;

    #pragma unroll
    for (int k = 0; k < 12; k++) {
        int d0 = (k * 8 + u) * 8;
        bf16x8 hp = *(const bf16x8*)(xrow + d0);
        bf16x8 rp = *(const bf16x8*)(xrow + DIM + d0);
        float bl[8];
        #pragma unroll
        for (int e = 0; e < 8; e++) {
            float hhv = (float)hp[e];
            float hrv = (float)rp[e];
            float df  = hhv - hrv;
            bl[e] = fmaf(a, df, hrv);
            l2 = fmaf(df, df, l2);
        }
        #pragma unroll
        for (int l = 0; l < NL; l++) {
            f32x4 wA = *(const f32x4*)(&hws[l * DIM + d0]);
            f32x4 wB = *(const f32x4*)(&hws[l * DIM + d0 + 4]);
            lg[l] += bl[0]*wA[0] + bl[1]*wA[1] + bl[2]*wA[2] + bl[3]*wA[3]
                   + bl[4]*wB[0] + bl[5]*wB[1] + bl[6]*wB[2] + bl[7]*wB[3];
        }
    }

    #pragma unroll
    for (int off = 1; off < 8; off <<= 1) {
        #pragma unroll
        for (int l = 0; l < NL; l++) lg[l] += __shfl_xor(lg[l], off);
        l2 += __shfl_xor(l2, off);
    }

    if (u < NL) {
        float v = (u == 0) ? lg[0] : (u == 1) ? lg[1] : (u == 2) ? lg[2]
                : (u == 3) ? lg[3] : (u == 4) ? lg[4] : (u == 5) ? lg[5] : lg[6];
        out[(size_t)tok * NL + u] = v + hb[u];
    } else {
        out[(size_t)NT * NL + NT + tok] = sqrtf(l2);
    }
}

// ---------------------------------------------------------------------------
extern "C" void kernel_launch(void* const* d_in, const int* in_sizes, int n_in,
                              void* d_out, int out_size, void* d_ws, size_t ws_size,
                              hipStream_t stream)
{
    const float* hh  = (const float*)d_in[0];
    const float* hr  = (const float*)d_in[1];
    const int*   idh = (const int*)d_in[2];
    const int*   idr = (const int*)d_in[3];
    const float* w1  = (const float*)d_in[5];
    const float* b1  = (const float*)d_in[6];
    const float* w2  = (const float*)d_in[7];
    const float* b2  = (const float*)d_in[8];
    const float* hw  = (const float*)d_in[9];
    const float* hb  = (const float*)d_in[10];
    float* out = (float*)d_out;

    bf16_t* X      = (bf16_t*)d_ws;                        // 50.33 MB
    bf16_t* w1t    = X + (size_t)NT * KDIM;                // 0.79 MB (tiled)
    int*    starts = (int*)(w1t + (size_t)NKT * HID * BK); // 263 KB

    convert_w1_kernel<<<192, 256, 0, stream>>>(w1, w1t);
    starts_kernel<<<128, 256, 0, stream>>>(idh, idr, starts);
    align_kernel<<<2048, 256, 0, stream>>>(hh, hr, starts, X);
    gemm_alpha_kernel<<<NT / BM, 256, 0, stream>>>(X, w1t, b1, w2, b2, out);
    blend_kernel<<<512, 256, 0, stream>>>(X, hw, hb, out);
}